// Round 5
// baseline (383.584 us; speedup 1.0000x reference)
//
#include <hip/hip_runtime.h>
#include <hip/hip_bf16.h>

typedef __bf16 bf16x8 __attribute__((ext_vector_type(8)));
typedef __bf16 bf16x2 __attribute__((ext_vector_type(2)));
typedef float f32x4 __attribute__((ext_vector_type(4)));

#define NROWS 100000
#define NSTRIPS 6250   // 100000 / 16, exact
#define EPS 1e-5f
#define SLOPE 0.2f

__device__ __forceinline__ bf16x8 cvt8(const float* s) {
    float4 x0 = *(const float4*)s, x1 = *(const float4*)(s + 4);
    bf16x8 o;
    o[0] = (__bf16)x0.x; o[1] = (__bf16)x0.y; o[2] = (__bf16)x0.z; o[3] = (__bf16)x0.w;
    o[4] = (__bf16)x1.x; o[5] = (__bf16)x1.y; o[6] = (__bf16)x1.z; o[7] = (__bf16)x1.w;
    return o;
}

// ---- streaming GEMM: Y = LeakyReLU(A @ W^T + bias), + column sum/sumsq --------
// Tall-skinny (M=100000, K,N<=256). Per block: 128 output columns
// (blockIdx.y selects which 128 of N). Per wave: 32 cols (NI=2), full K of W
// in registers. A streams global->MFMA A-frags. No LDS, no barriers.
// WPE = min waves/EU = resident blocks/CU target (register cap 512/WPE).
template <int KT, int NROWSTRIDE, bool F32IN, int WPE>
__global__ __launch_bounds__(256, WPE)
void gemm_stream(const __bf16* __restrict__ A, const float* __restrict__ A32,
                 const __bf16* __restrict__ W, const float* __restrict__ W32,
                 const float* __restrict__ bias, __bf16* __restrict__ Y,
                 float* __restrict__ sum, float* __restrict__ sumsq)
{
    constexpr int KS = KT / 32;
    constexpr int NI = 2;
    const int wave = threadIdx.x >> 6, lane = threadIdx.x & 63;
    const int quad = lane >> 4, l16 = lane & 15;
    const int c0 = blockIdx.y * 128 + wave * 32;

    // W-fragments for this wave's 32 columns, full K, in registers
    bf16x8 bfrag[NI][KS];
    float bcol[NI];
    #pragma unroll
    for (int ni = 0; ni < NI; ++ni) {
        int col = c0 + ni * 16 + l16;
        bcol[ni] = bias[col];
        #pragma unroll
        for (int ks = 0; ks < KS; ++ks) {
            int k = ks * 32 + quad * 8;
            if constexpr (F32IN) bfrag[ni][ks] = cvt8(W32 + (size_t)col * KT + k);
            else                 bfrag[ni][ks] = *(const bf16x8*)(W + (size_t)col * KT + k);
        }
    }

    float csum[NI] = {}, csq[NI] = {};

    for (int s = blockIdx.x; s < NSTRIPS; s += gridDim.x) {
        int row0 = s * 16;
        bf16x8 afrag[KS];
        #pragma unroll
        for (int ks = 0; ks < KS; ++ks) {
            int k = ks * 32 + quad * 8;
            if constexpr (F32IN) afrag[ks] = cvt8(A32 + (size_t)(row0 + l16) * KT + k);
            else                 afrag[ks] = *(const bf16x8*)(A + (size_t)(row0 + l16) * KT + k);
        }
        f32x4 acc[NI] = {};
        #pragma unroll
        for (int ks = 0; ks < KS; ++ks)
            #pragma unroll
            for (int ni = 0; ni < NI; ++ni)
                acc[ni] = __builtin_amdgcn_mfma_f32_16x16x32_bf16(
                    afrag[ks], bfrag[ni][ks], acc[ni], 0, 0, 0);

        #pragma unroll
        for (int ni = 0; ni < NI; ++ni) {
            int col = c0 + ni * 16 + l16;
            #pragma unroll
            for (int r = 0; r < 4; ++r) {
                float y = acc[ni][r] + bcol[ni];
                y = (y > 0.f) ? y : SLOPE * y;
                Y[(size_t)(row0 + quad * 4 + r) * NROWSTRIDE + col] = (__bf16)y;
                csum[ni] += y;
                csq[ni]  += y * y;
            }
        }
    }

    #pragma unroll
    for (int ni = 0; ni < NI; ++ni) {
        float s = csum[ni], q = csq[ni];
        s += __shfl_xor(s, 16); s += __shfl_xor(s, 32);
        q += __shfl_xor(q, 16); q += __shfl_xor(q, 32);
        if (quad == 0) {
            int col = c0 + ni * 16 + l16;
            atomicAdd(&sum[col], s);
            atomicAdd(&sumsq[col], q);
        }
    }
}

// ---- fused stats+fold: s=g*rsqrt(var+eps), t=beta-m*s (LDS), then
//      W' = W*diag(s) (bf16), b' = b + W@t. K=256 always here. ----------------
__global__ __launch_bounds__(256)
void fold_bn(const float* __restrict__ sum, const float* __restrict__ sumsq,
             const float* __restrict__ g, const float* __restrict__ beta,
             const float* __restrict__ W, const float* __restrict__ b,
             __bf16* __restrict__ Wf, float* __restrict__ bf_,
             int Nrows, float invN)
{
    __shared__ float sS[256], sT[256];
    const int t = threadIdx.x;
    {
        float m = sum[t] * invN;
        float v = sumsq[t] * invN - m * m;
        float sc = g[t] * rsqrtf(v + EPS);
        sS[t] = sc;
        sT[t] = beta[t] - m * sc;
    }
    __syncthreads();
    const int wave = t >> 6, lane = t & 63;
    for (int n = blockIdx.x * 4 + wave; n < Nrows; n += gridDim.x * 4) {
        float dot = 0.f;
        #pragma unroll
        for (int kk = 0; kk < 4; ++kk) {
            int k = kk * 64 + lane;
            float w = W[(size_t)n * 256 + k];
            Wf[(size_t)n * 256 + k] = (__bf16)(w * sS[k]);
            dot += w * sT[k];
        }
        #pragma unroll
        for (int off = 32; off; off >>= 1) dot += __shfl_down(dot, off);
        if (lane == 0) bf_[n] = b[n] + dot;
    }
}

// ------------- stats for layer 3 (s3,t3 must be materialized) --------------------
__global__ void stats_k(const float* __restrict__ sum, const float* __restrict__ sumsq,
                        const float* __restrict__ g, const float* __restrict__ beta,
                        float* __restrict__ s, float* __restrict__ t,
                        int Ncols, float invN)
{
    int c = blockIdx.x * blockDim.x + threadIdx.x;
    if (c < Ncols) {
        float m = sum[c] * invN;
        float v = sumsq[c] * invN - m * m;
        float sc = g[c] * rsqrtf(v + EPS);
        s[c] = sc;
        t[c] = beta[c] - m * sc;
    }
}

// ---- finalize: per row, F = Y3*s3+t3 (fp32) AND node_update = BN(mean of
//      16 gathered pre-BN Y3 rows) — mean/BN commute (affine is linear). ------
__global__ __launch_bounds__(256)
void finalize(const __bf16* __restrict__ Y3, const int* __restrict__ idx,
              const float* __restrict__ s3, const float* __restrict__ t3,
              float* __restrict__ out, float* __restrict__ F, int N)
{
    int row = blockIdx.x * 4 + (threadIdx.x >> 6);  // one row per wave
    if (row >= N) return;
    int lane = threadIdx.x & 63;
    float2 sc = *(const float2*)(s3 + lane * 2);
    float2 tc = *(const float2*)(t3 + lane * 2);

    // gather loads (long latency — issue first)
    const int* ib = idx + (size_t)row * 16;
    float a0 = 0.f, a1 = 0.f;
    #pragma unroll
    for (int k = 0; k < 16; ++k) {
        int j = ib[k];  // wave-uniform -> scalar load
        bf16x2 v = *(const bf16x2*)(Y3 + (size_t)j * 128 + lane * 2);
        a0 += (float)v[0];
        a1 += (float)v[1];
    }

    // own-row BN -> fp32 F
    bf16x2 mv = *(const bf16x2*)(Y3 + (size_t)row * 128 + lane * 2);
    float2 fo;
    fo.x = (float)mv[0] * sc.x + tc.x;
    fo.y = (float)mv[1] * sc.y + tc.y;
    *(float2*)(F + (size_t)row * 128 + lane * 2) = fo;

    float2 o;
    o.x = a0 * 0.0625f * sc.x + tc.x;
    o.y = a1 * 0.0625f * sc.y + tc.y;
    *(float2*)(out + (size_t)row * 128 + lane * 2) = o;
}

extern "C" void kernel_launch(void* const* d_in, const int* in_sizes, int n_in,
                              void* d_out, int out_size, void* d_ws, size_t ws_size,
                              hipStream_t stream)
{
    const float* X   = (const float*)d_in[0];
    const int*   idx = (const int*)d_in[1];
    // d_in[2] = prob_retained (unused, ==1)
    const float* W1  = (const float*)d_in[3];
    const float* b1  = (const float*)d_in[4];
    const float* g1  = (const float*)d_in[5];
    const float* be1 = (const float*)d_in[6];
    const float* W2  = (const float*)d_in[7];
    const float* b2  = (const float*)d_in[8];
    const float* g2  = (const float*)d_in[9];
    const float* be2 = (const float*)d_in[10];
    const float* W3  = (const float*)d_in[11];
    const float* b3  = (const float*)d_in[12];
    const float* g3  = (const float*)d_in[13];
    const float* be3 = (const float*)d_in[14];

    char* ws = (char*)d_ws;
    float* sum1 = (float*)(ws + 0);
    float* sq1  = (float*)(ws + 1024);
    float* sum2 = (float*)(ws + 2048);
    float* sq2  = (float*)(ws + 3072);
    float* sum3 = (float*)(ws + 4096);
    float* sq3  = (float*)(ws + 4608);
    float* s3   = (float*)(ws + 9216);
    float* t3   = (float*)(ws + 9728);
    float* b2f  = (float*)(ws + 10240);
    float* b3f  = (float*)(ws + 11264);
    __bf16* W2f = (__bf16*)(ws + 13312);            // 256*256*2 = 131072 B
    __bf16* W3f = (__bf16*)(ws + 144384);           // 128*256*2 = 65536 B
    __bf16* Y1  = (__bf16*)(ws + (1 << 20));                   // [N,256] bf16 51.2 MB
    __bf16* Y2  = (__bf16*)(ws + (1 << 20) + 51200000);        // [N,256] bf16 51.2 MB
    __bf16* Y3  = Y1;  // [N,128]; Y1 dead after gemm2 (gemm3 reads only Y2)

    float* out_nu = (float*)d_out;                  // node_update [N,128] fp32
    float* F      = out_nu + (size_t)NROWS * 128;   // f [N,128] fp32

    const float invN = 1.0f / (float)NROWS;
    const dim3 blk(256);

    hipMemsetAsync(d_ws, 0, 5120, stream);  // zero sum/sumsq accumulators

    // layer 1: X[100000,128] @ W1[256,128]^T (fp32 inline cvt). 4 blocks/CU.
    gemm_stream<128, 256, true, 4><<<dim3(512, 2), blk, 0, stream>>>(
        nullptr, X, nullptr, W1, b1, Y1, sum1, sq1);
    fold_bn<<<64, blk, 0, stream>>>(sum1, sq1, g1, be1, W2, b2, W2f, b2f, 256, invN);

    // layer 2: Y1[100000,256] @ W2'[256,256]^T -> Y2. 3 blocks/CU (reg budget).
    gemm_stream<256, 256, false, 3><<<dim3(384, 2), blk, 0, stream>>>(
        Y1, nullptr, W2f, nullptr, b2f, Y2, sum2, sq2);
    fold_bn<<<32, blk, 0, stream>>>(sum2, sq2, g2, be2, W3, b3, W3f, b3f, 128, invN);

    // layer 3: Y2[100000,256] @ W3'[128,256]^T -> raw Y3 (pre-BN) into Y1 region
    gemm_stream<256, 128, false, 3><<<dim3(768, 1), blk, 0, stream>>>(
        Y2, nullptr, W3f, nullptr, b3f, Y3, sum3, sq3);
    stats_k<<<1, 128, 0, stream>>>(sum3, sq3, g3, be3, s3, t3, 128, invN);

    // fused: F = BN(Y3) fp32 into d_out; node_update = BN(gather-mean(Y3))
    finalize<<<25000, blk, 0, stream>>>(Y3, idx, s3, t3, out_nu, F, NROWS);
}